// Round 16
// baseline (378.932 us; speedup 1.0000x reference)
//
#include <hip/hip_runtime.h>
#include <hip/hip_bf16.h>
#include <stdint.h>

// ---------------------------------------------------------------------------
// MultiheadAttention (B=2,S=2048,E=2048,H=16,D=128), softcap=50, alpha=1
// Inputs FP32, output FP32, dict-order labels (proven r8-r15).
// Round 16: attn KVBLK=128 (16 tiles: kills the measured 2.6us/tile fixed
// cost), single-buffer staggered async staging (K dead after QK, V dead
// after PV; counted vmcnt(8) + raw s_barrier), global_load_lds with
// pre-swizzled global source (m173), XCD-chunked block swizzle (L2-fit).
// QKV GEMMs fused into one z=3 dispatch. GEMM structure (m97) unchanged.
// ---------------------------------------------------------------------------

typedef __attribute__((ext_vector_type(8))) short s16x8;   // 8 bf16
typedef __attribute__((ext_vector_type(4))) float f32x4;

typedef const __attribute__((address_space(1))) char* gcptr;
typedef __attribute__((address_space(3))) char* lcptr;

#define MFMA_BF16(a, b, c) __builtin_amdgcn_mfma_f32_16x16x32_bf16((a), (b), (c), 0, 0, 0)

__device__ __forceinline__ short f2bf(float f) {          // fp32 -> bf16 RNE
  union { float f; unsigned u; } x; x.f = f;
  unsigned r = (x.u + 0x7fffu + ((x.u >> 16) & 1u)) >> 16;
  return (short)r;
}

__device__ __forceinline__ void gload16(const void* g, void* lds) {
  __builtin_amdgcn_global_load_lds((gcptr)g, (lcptr)lds, 16, 0, 0);
}

constexpr int GK = 2048;
constexpr int SL = 2048, EMB = 2048, HD = 128;

// ---------------------------------------------------------------------------
// Merged fp32 -> bf16 conversion for all 7 inputs (dst contiguous in ws).
// ---------------------------------------------------------------------------
__global__ void cvt_all(const float* __restrict__ q, const float* __restrict__ k,
                        const float* __restrict__ v, const float* __restrict__ wq,
                        const float* __restrict__ wk, const float* __restrict__ wv,
                        const float* __restrict__ wo, short* __restrict__ dst) {
  const int N8A = 1 << 20, N8W = 1 << 19;
  const int total = 3 * N8A + 4 * N8W;
  int i = blockIdx.x * blockDim.x + threadIdx.x;
  int stride = gridDim.x * blockDim.x;
  for (; i < total; i += stride) {
    const float* src;
    size_t loc;
    if (i < 3 * N8A) {
      int sel = i >> 20;
      loc = (size_t)(i & (N8A - 1));
      src = sel == 0 ? q : (sel == 1 ? k : v);
    } else {
      int w = i - 3 * N8A;
      int sel = w >> 19;
      loc = (size_t)(w & (N8W - 1));
      src = sel == 0 ? wq : (sel == 1 ? wk : (sel == 2 ? wv : wo));
    }
    f32x4 a = *reinterpret_cast<const f32x4*>(src + loc * 8);
    f32x4 b = *reinterpret_cast<const f32x4*>(src + loc * 8 + 4);
    s16x8 w8;
#pragma unroll
    for (int j = 0; j < 4; ++j) { w8[j] = f2bf(a[j]); w8[4 + j] = f2bf(b[j]); }
    *reinterpret_cast<s16x8*>(dst + (size_t)i * 8) = w8;
  }
}

// ---------------------------------------------------------------------------
// Fused QKV GEMM (z selects Q/K/V^T), m97 structure, bf16 out.
// z=0,1: C[m,n] = A[m,k]B[n,k], M=4096,N=2048. z=2: VpT (A=Wv,B=v), M=2048,
// N=4096 (bm/bn roles swapped so one grid serves all three).
// ---------------------------------------------------------------------------
__global__ __launch_bounds__(256, 2)
void gemm_qkv(const short* __restrict__ a0, const short* __restrict__ a1,
              const short* __restrict__ w0, const short* __restrict__ w1,
              const short* __restrict__ w2, const short* __restrict__ a2,
              short* __restrict__ o0, short* __restrict__ o1,
              short* __restrict__ o2) {
  __shared__ __align__(16) short As[128 * 64];
  __shared__ __align__(16) short Bs[128 * 64];
  const int z = blockIdx.z;
  const short* A = z == 0 ? a0 : (z == 1 ? a1 : w2);   // z=2: A=Wv
  const short* B = z == 0 ? w0 : (z == 1 ? w1 : a2);   // z=2: B=v
  short* C = z == 0 ? o0 : (z == 1 ? o1 : o2);
  const int bm = z == 2 ? blockIdx.x : blockIdx.y;
  const int bn = z == 2 ? blockIdx.y : blockIdx.x;
  const int gn = z == 2 ? 4096 : 2048;

  const int tid = threadIdx.x;
  const int lane = tid & 63;
  const int wid = tid >> 6;
  const int wr = wid >> 1, wc = wid & 1;
  const int g = lane >> 4, r = lane & 15;

  const f32x4 fz = {0.f, 0.f, 0.f, 0.f};
  f32x4 acc[4][4];
#pragma unroll
  for (int m = 0; m < 4; ++m)
#pragma unroll
    for (int n = 0; n < 4; ++n) acc[m][n] = fz;

  const short* Ab = A + (size_t)bm * 128 * GK;
  const short* Bb = B + (size_t)bn * 128 * GK;

  for (int kt = 0; kt < GK; kt += 64) {
#pragma unroll
    for (int i = 0; i < 4; ++i) {
      int c = i * 256 + tid;
      int row = c >> 3, c8 = c & 7;
      gload16(Ab + (size_t)row * GK + kt + c8 * 8, As + c * 8);
      gload16(Bb + (size_t)row * GK + kt + c8 * 8, Bs + c * 8);
    }
    __syncthreads();
#pragma unroll
    for (int kk = 0; kk < 2; ++kk) {
      s16x8 af[4], bf[4];
#pragma unroll
      for (int m = 0; m < 4; ++m)
        af[m] = *reinterpret_cast<const s16x8*>(As + (wr * 64 + m * 16 + r) * 64 + kk * 32 + g * 8);
#pragma unroll
      for (int n = 0; n < 4; ++n)
        bf[n] = *reinterpret_cast<const s16x8*>(Bs + (wc * 64 + n * 16 + r) * 64 + kk * 32 + g * 8);
#pragma unroll
      for (int m = 0; m < 4; ++m)
#pragma unroll
        for (int n = 0; n < 4; ++n) acc[m][n] = MFMA_BF16(af[m], bf[n], acc[m][n]);
    }
    __syncthreads();
  }

#pragma unroll
  for (int m = 0; m < 4; ++m)
#pragma unroll
    for (int j = 0; j < 4; ++j) {
      int crow = bm * 128 + wr * 64 + m * 16 + g * 4 + j;
      size_t off = (size_t)crow * gn + bn * 128 + wc * 64 + r;
#pragma unroll
      for (int n = 0; n < 4; ++n) C[off + n * 16] = f2bf(acc[m][n][j]);
    }
}

// ---------------------------------------------------------------------------
// Final GEMM (ctx @ Wo^T), m97 structure, fp32 out.
// ---------------------------------------------------------------------------
__global__ __launch_bounds__(256, 2)
void gemm_out(const short* __restrict__ A, const short* __restrict__ B,
              float* __restrict__ C) {
  __shared__ __align__(16) short As[128 * 64];
  __shared__ __align__(16) short Bs[128 * 64];
  const int tid = threadIdx.x;
  const int lane = tid & 63;
  const int wid = tid >> 6;
  const int wr = wid >> 1, wc = wid & 1;
  const int g = lane >> 4, r = lane & 15;
  const int bm = blockIdx.y, bn = blockIdx.x;

  const f32x4 fz = {0.f, 0.f, 0.f, 0.f};
  f32x4 acc[4][4];
#pragma unroll
  for (int m = 0; m < 4; ++m)
#pragma unroll
    for (int n = 0; n < 4; ++n) acc[m][n] = fz;

  const short* Ab = A + (size_t)bm * 128 * GK;
  const short* Bb = B + (size_t)bn * 128 * GK;

  for (int kt = 0; kt < GK; kt += 64) {
#pragma unroll
    for (int i = 0; i < 4; ++i) {
      int c = i * 256 + tid;
      int row = c >> 3, c8 = c & 7;
      gload16(Ab + (size_t)row * GK + kt + c8 * 8, As + c * 8);
      gload16(Bb + (size_t)row * GK + kt + c8 * 8, Bs + c * 8);
    }
    __syncthreads();
#pragma unroll
    for (int kk = 0; kk < 2; ++kk) {
      s16x8 af[4], bf[4];
#pragma unroll
      for (int m = 0; m < 4; ++m)
        af[m] = *reinterpret_cast<const s16x8*>(As + (wr * 64 + m * 16 + r) * 64 + kk * 32 + g * 8);
#pragma unroll
      for (int n = 0; n < 4; ++n)
        bf[n] = *reinterpret_cast<const s16x8*>(Bs + (wc * 64 + n * 16 + r) * 64 + kk * 32 + g * 8);
#pragma unroll
      for (int m = 0; m < 4; ++m)
#pragma unroll
        for (int n = 0; n < 4; ++n) acc[m][n] = MFMA_BF16(af[m], bf[n], acc[m][n]);
    }
    __syncthreads();
  }

#pragma unroll
  for (int m = 0; m < 4; ++m)
#pragma unroll
    for (int j = 0; j < 4; ++j) {
      int crow = bm * 128 + wr * 64 + m * 16 + g * 4 + j;
      size_t off = (size_t)crow * 2048 + bn * 128 + wc * 64 + r;
#pragma unroll
      for (int n = 0; n < 4; ++n) C[off + n * 16] = acc[m][n][j];
    }
}

// ---------------------------------------------------------------------------
// MFMA flash attention — 4 waves / 256 threads; 32 q-rows/wave; KVBLK=128
// (16 tiles). Single-buffer staggered async staging: K(t) dead after QK,
// V(t) dead after PV; counted vmcnt(8) + raw s_barrier (no __syncthreads,
// which would drain vmcnt to 0). K/V staged by global_load_lds with
// pre-swizzled GLOBAL source chunk ch^(row&7), linear LDS dest; reads
// un-swizzle with the same involution (2-way banks). XCD-chunked swizzle.
// ---------------------------------------------------------------------------
__global__ __launch_bounds__(256, 1)
void attn(const short* __restrict__ Q, const short* __restrict__ K,
          const short* __restrict__ VT, short* __restrict__ O) {
  __shared__ __align__(16) short Ks[128 * 128];     // rows kv, cols d (chunks)
  __shared__ __align__(16) short Vt[128 * 128];     // rows d,  cols kv
  __shared__ __align__(16) short Ps[4 * 2 * 16 * 136];

  const int tid = threadIdx.x;
  const int lane = tid & 63;
  const int wid = tid >> 6;                  // 0..3
  const int g = lane >> 4, r = lane & 15;

  // XCD-chunked bijective swizzle (512 blocks, 512%8==0): XCD n hosts 4
  // consecutive bh values -> K/V working set 2MB/XCD (L2-fit).
  const int dflat = blockIdx.x + (blockIdx.y << 4);
  const int cflat = ((dflat & 7) << 6) + (dflat >> 3);
  const int qb = cflat & 15;
  const int bh = cflat >> 4;
  const int b = bh >> 4, h = bh & 15;
  const size_t base = (size_t)b * SL * EMB + (size_t)h * HD;
  const size_t vbase = (size_t)h * HD * 4096 + (size_t)b * SL;

  const int q0 = qb * 128 + wid * 32;        // wave's 32 q-rows
  s16x8 qf[2][4];
#pragma unroll
  for (int s = 0; s < 2; ++s)
#pragma unroll
    for (int kk = 0; kk < 4; ++kk)
      qf[s][kk] = *reinterpret_cast<const s16x8*>(
          Q + base + (size_t)(q0 + s * 16 + r) * EMB + kk * 32 + g * 8);

  const f32x4 fz = {0.f, 0.f, 0.f, 0.f};
  float l_run[2][4];
  f32x4 acc_o[2][8];
#pragma unroll
  for (int s = 0; s < 2; ++s) {
#pragma unroll
    for (int i = 0; i < 4; ++i) l_run[s][i] = 0.f;
#pragma unroll
    for (int i = 0; i < 8; ++i) acc_o[s][i] = fz;
  }

  const float SCALE = 0.08838834764831845f;  // 1/sqrt(128)
  const float C50I = 0.02f;                  // 1/50
  const float CA = -1.f / 3.f, CB = 2.f / 15.f;

  const int n0 = (wid << 6) + lane;          // staging: n = n0 + i*256
  // stage K tile t: 2048 chunks, 8 issues/thread, linear LDS dest,
  // pre-swizzled global source (content at phys chunk ch is logical ch^(rr&7))
  auto stageK = [&](int t) {
    const int kv0 = t * 128;
#pragma unroll
    for (int i = 0; i < 8; ++i) {
      int n = n0 + i * 256;
      int rr = n >> 4, ch = n & 15;
      int lch = ch ^ (rr & 7);
      gload16(K + base + (size_t)(kv0 + rr) * EMB + lch * 8, Ks + n * 8);
    }
  };
  auto stageV = [&](int t) {
    const int kv0 = t * 128;
#pragma unroll
    for (int i = 0; i < 8; ++i) {
      int n = n0 + i * 256;
      int rr = n >> 4, ch = n & 15;       // rr = d row
      int lch = ch ^ (rr & 7);
      gload16(VT + vbase + (size_t)rr * 4096 + kv0 + lch * 8, Vt + n * 8);
    }
  };

  stageK(0);
  stageV(0);

  const int psb = (wid * 2) * 16 * 136;      // wave's Ps base (set stride below)

  for (int t = 0; t < SL / 128; ++t) {
    // ---- own K(t) landed (8 newest = V(t)-or-later allowed outstanding) ----
    asm volatile("s_waitcnt vmcnt(8)" ::: "memory");
    __builtin_amdgcn_s_barrier();            // all waves' K(t) landed

    // ---- S = Q K^T (kn 0..7), reads un-swizzle chunks ----
    f32x4 sv[2][8];
#pragma unroll
    for (int kn = 0; kn < 8; ++kn) {
      sv[0][kn] = fz; sv[1][kn] = fz;
#pragma unroll
      for (int kk = 0; kk < 4; ++kk) {
        const s16x8 kf = *reinterpret_cast<const s16x8*>(
            Ks + ((kn * 16 + r) * 16 + ((kk * 4 + g) ^ (r & 7))) * 8);
        sv[0][kn] = MFMA_BF16(qf[0][kk], kf, sv[0][kn]);
        sv[1][kn] = MFMA_BF16(qf[1][kk], kf, sv[1][kn]);
      }
    }
    asm volatile("s_waitcnt lgkmcnt(0)" ::: "memory");
    __builtin_amdgcn_s_barrier();            // all waves done reading Ks(t)
    stageK((t + 1) & 15);                    // overwrite Ks asynchronously

    // ---- poly softcap + fixed-max-50 softmax (lane-local) + Ps write ----
#pragma unroll
    for (int s = 0; s < 2; ++s)
#pragma unroll
      for (int kn = 0; kn < 8; ++kn)
#pragma unroll
        for (int reg = 0; reg < 4; ++reg) {
          float z = sv[s][kn][reg] * SCALE;
          float x = z * C50I;
          float x2 = x * x;
          float poly = __builtin_fmaf(x2, __builtin_fmaf(x2, CB, CA), 1.f);
          float cap = fminf(z * poly, 50.f);
          float pe = __expf(cap - 50.f);
          l_run[s][reg] += pe;
          Ps[psb + s * 16 * 136 + (g * 4 + reg) * 136 + kn * 16 + r] = f2bf(pe);
        }

    // ---- own V(t) landed (8 newest = K(t+1) allowed outstanding) ----
    asm volatile("s_waitcnt vmcnt(8)" ::: "memory");
    __builtin_amdgcn_s_barrier();            // all waves' V(t) landed

    // ---- O += P V ----
#pragma unroll
    for (int c = 0; c < 4; ++c) {
      const s16x8 pa0 = *reinterpret_cast<const s16x8*>(
          Ps + psb + 0 * 16 * 136 + r * 136 + c * 32 + g * 8);
      const s16x8 pa1 = *reinterpret_cast<const s16x8*>(
          Ps + psb + 1 * 16 * 136 + r * 136 + c * 32 + g * 8);
#pragma unroll
      for (int dn = 0; dn < 8; ++dn) {
        const int d = dn * 16 + r;
        const s16x8 vf = *reinterpret_cast<const s16x8*>(
            Vt + (d * 16 + ((c * 4 + g) ^ (r & 7))) * 8);
        acc_o[0][dn] = MFMA_BF16(pa0, vf, acc_o[0][dn]);
        acc_o[1][dn] = MFMA_BF16(pa1, vf, acc_o[1][dn]);
      }
    }
    asm volatile("s_waitcnt lgkmcnt(0)" ::: "memory");
    __builtin_amdgcn_s_barrier();            // all waves done reading Vt(t)
    stageV((t + 1) & 15);                    // overwrite Vt asynchronously
  }

  asm volatile("s_waitcnt vmcnt(0)" ::: "memory");  // quiesce dangling gloads

  // ---- deferred l reduction + epilogue ----
#pragma unroll
  for (int s = 0; s < 2; ++s) {
#pragma unroll
    for (int reg = 0; reg < 4; ++reg) {
#pragma unroll
      for (int off = 1; off < 16; off <<= 1)
        l_run[s][reg] += __shfl_xor(l_run[s][reg], off);
      l_run[s][reg] = 1.f / l_run[s][reg];
    }
#pragma unroll
    for (int dn = 0; dn < 8; ++dn)
#pragma unroll
      for (int reg = 0; reg < 4; ++reg) {
        int row = q0 + s * 16 + g * 4 + reg;
        O[base + (size_t)row * EMB + dn * 16 + r] = f2bf(acc_o[s][dn][reg] * l_run[s][reg]);
      }
  }
}

__global__ void fill_f32(float* p, int n, float val) {
  int i = blockIdx.x * blockDim.x + threadIdx.x;
  if (i < n) p[i] = val;
}

// ---------------------------------------------------------------------------
extern "C" void kernel_launch(void* const* d_in, const int* in_sizes, int n_in,
                              void* d_out, int out_size, void* d_ws, size_t ws_size,
                              hipStream_t stream) {
  const float* q  = (const float*)d_in[0];
  const float* k  = (const float*)d_in[1];
  const float* v  = (const float*)d_in[2];
  const float* wq = (const float*)d_in[3];
  const float* wk = (const float*)d_in[4];
  const float* wv = (const float*)d_in[5];
  const float* wo = (const float*)d_in[6];
  float* out = (float*)d_out;

  bool ok = (n_in == 7) && out_size == 8388608;
  for (int i = 0; i < 3 && ok; ++i) ok = (in_sizes[i] == 8388608);
  for (int i = 3; i < 7 && ok; ++i) ok = (in_sizes[i] == 4194304);
  if (!ok) {
    fill_f32<<<(out_size + 255) / 256, 256, 0, stream>>>(out, out_size, 150.f);
    return;
  }

  const size_t NA = 8388608;
  const size_t NW = 4194304;
  const size_t need = (3 * NA + 4 * NW + 4 * NA) * sizeof(short); // 144 MiB
  if (ws_size < need) {
    fill_f32<<<(out_size + 255) / 256, 256, 0, stream>>>(out, out_size, 128.f);
    return;
  }

  short* bq  = (short*)d_ws;                 // cvt dst, contiguous
  short* bk  = bq + NA;
  short* bv  = bk + NA;
  short* bwq = bv + NA;
  short* bwk = bwq + NW;
  short* bwv = bwk + NW;
  short* bwo = bwv + NW;
  short* Qp  = bwo + NW;
  short* Kp  = Qp + NA;
  short* VpT = Kp + NA;                      // [2048 features][4096 tokens]
  short* Cx  = VpT + NA;

  dim3 blk(256);
  dim3 g3(16, 32, 3);                        // fused QKV
  dim3 gg(16, 32);                           // out GEMM
  dim3 ga(16, 32);                           // attn: 512 blocks

  cvt_all<<<2048, 256, 0, stream>>>(q, k, v, wq, wk, wv, wo, bq);
  gemm_qkv<<<g3, blk, 0, stream>>>(bq, bk, bwq, bwk, bwv, bv, Qp, Kp, VpT);
  attn<<<ga, blk, 0, stream>>>(Qp, Kp, VpT, Cx);
  gemm_out<<<gg, blk, 0, stream>>>(Cx, bwo, out);
}

// Round 17
// 339.830 us; speedup vs baseline: 1.1151x; 1.1151x over previous
//
#include <hip/hip_runtime.h>
#include <hip/hip_bf16.h>
#include <stdint.h>

// ---------------------------------------------------------------------------
// MultiheadAttention (B=2,S=2048,E=2048,H=16,D=128), softcap=50, alpha=1
// Inputs FP32, output FP32, dict-order labels (proven r8-r16).
// Round 17: attn reverted to r15 structure (KVBLK=64, T14 prefetch, b128
// V-staging — best measured: 131us) + the two r16-PROVEN grafts:
//   (1) XCD-chunked block swizzle: K/V L2-resident (FETCH 139->25MB in r16)
//   (2) fused z=3 QKV GEMM dispatch (2 fewer launch gaps)
// ---------------------------------------------------------------------------

typedef __attribute__((ext_vector_type(8))) short s16x8;   // 8 bf16
typedef __attribute__((ext_vector_type(4))) float f32x4;

typedef const __attribute__((address_space(1))) char* gcptr;
typedef __attribute__((address_space(3))) char* lcptr;

#define MFMA_BF16(a, b, c) __builtin_amdgcn_mfma_f32_16x16x32_bf16((a), (b), (c), 0, 0, 0)

__device__ __forceinline__ short f2bf(float f) {          // fp32 -> bf16 RNE
  union { float f; unsigned u; } x; x.f = f;
  unsigned r = (x.u + 0x7fffu + ((x.u >> 16) & 1u)) >> 16;
  return (short)r;
}

__device__ __forceinline__ void gload16(const void* g, void* lds) {
  __builtin_amdgcn_global_load_lds((gcptr)g, (lcptr)lds, 16, 0, 0);
}

constexpr int GK = 2048;
constexpr int SL = 2048, EMB = 2048, HD = 128;

// ---------------------------------------------------------------------------
// Merged fp32 -> bf16 conversion for all 7 inputs (dst contiguous in ws).
// ---------------------------------------------------------------------------
__global__ void cvt_all(const float* __restrict__ q, const float* __restrict__ k,
                        const float* __restrict__ v, const float* __restrict__ wq,
                        const float* __restrict__ wk, const float* __restrict__ wv,
                        const float* __restrict__ wo, short* __restrict__ dst) {
  const int N8A = 1 << 20, N8W = 1 << 19;
  const int total = 3 * N8A + 4 * N8W;
  int i = blockIdx.x * blockDim.x + threadIdx.x;
  int stride = gridDim.x * blockDim.x;
  for (; i < total; i += stride) {
    const float* src;
    size_t loc;
    if (i < 3 * N8A) {
      int sel = i >> 20;
      loc = (size_t)(i & (N8A - 1));
      src = sel == 0 ? q : (sel == 1 ? k : v);
    } else {
      int w = i - 3 * N8A;
      int sel = w >> 19;
      loc = (size_t)(w & (N8W - 1));
      src = sel == 0 ? wq : (sel == 1 ? wk : (sel == 2 ? wv : wo));
    }
    f32x4 a = *reinterpret_cast<const f32x4*>(src + loc * 8);
    f32x4 b = *reinterpret_cast<const f32x4*>(src + loc * 8 + 4);
    s16x8 w8;
#pragma unroll
    for (int j = 0; j < 4; ++j) { w8[j] = f2bf(a[j]); w8[4 + j] = f2bf(b[j]); }
    *reinterpret_cast<s16x8*>(dst + (size_t)i * 8) = w8;
  }
}

// ---------------------------------------------------------------------------
// Fused QKV GEMM (z selects Q/K/V^T), m97 structure, bf16 out. (r16-proven)
// ---------------------------------------------------------------------------
__global__ __launch_bounds__(256, 2)
void gemm_qkv(const short* __restrict__ a0, const short* __restrict__ a1,
              const short* __restrict__ w0, const short* __restrict__ w1,
              const short* __restrict__ w2, const short* __restrict__ a2,
              short* __restrict__ o0, short* __restrict__ o1,
              short* __restrict__ o2) {
  __shared__ __align__(16) short As[128 * 64];
  __shared__ __align__(16) short Bs[128 * 64];
  const int z = blockIdx.z;
  const short* A = z == 0 ? a0 : (z == 1 ? a1 : w2);   // z=2: A=Wv
  const short* B = z == 0 ? w0 : (z == 1 ? w1 : a2);   // z=2: B=v
  short* C = z == 0 ? o0 : (z == 1 ? o1 : o2);
  const int bm = z == 2 ? blockIdx.x : blockIdx.y;
  const int bn = z == 2 ? blockIdx.y : blockIdx.x;
  const int gn = z == 2 ? 4096 : 2048;

  const int tid = threadIdx.x;
  const int lane = tid & 63;
  const int wid = tid >> 6;
  const int wr = wid >> 1, wc = wid & 1;
  const int g = lane >> 4, r = lane & 15;

  const f32x4 fz = {0.f, 0.f, 0.f, 0.f};
  f32x4 acc[4][4];
#pragma unroll
  for (int m = 0; m < 4; ++m)
#pragma unroll
    for (int n = 0; n < 4; ++n) acc[m][n] = fz;

  const short* Ab = A + (size_t)bm * 128 * GK;
  const short* Bb = B + (size_t)bn * 128 * GK;

  for (int kt = 0; kt < GK; kt += 64) {
#pragma unroll
    for (int i = 0; i < 4; ++i) {
      int c = i * 256 + tid;
      int row = c >> 3, c8 = c & 7;
      gload16(Ab + (size_t)row * GK + kt + c8 * 8, As + c * 8);
      gload16(Bb + (size_t)row * GK + kt + c8 * 8, Bs + c * 8);
    }
    __syncthreads();
#pragma unroll
    for (int kk = 0; kk < 2; ++kk) {
      s16x8 af[4], bf[4];
#pragma unroll
      for (int m = 0; m < 4; ++m)
        af[m] = *reinterpret_cast<const s16x8*>(As + (wr * 64 + m * 16 + r) * 64 + kk * 32 + g * 8);
#pragma unroll
      for (int n = 0; n < 4; ++n)
        bf[n] = *reinterpret_cast<const s16x8*>(Bs + (wc * 64 + n * 16 + r) * 64 + kk * 32 + g * 8);
#pragma unroll
      for (int m = 0; m < 4; ++m)
#pragma unroll
        for (int n = 0; n < 4; ++n) acc[m][n] = MFMA_BF16(af[m], bf[n], acc[m][n]);
    }
    __syncthreads();
  }

#pragma unroll
  for (int m = 0; m < 4; ++m)
#pragma unroll
    for (int j = 0; j < 4; ++j) {
      int crow = bm * 128 + wr * 64 + m * 16 + g * 4 + j;
      size_t off = (size_t)crow * gn + bn * 128 + wc * 64 + r;
#pragma unroll
      for (int n = 0; n < 4; ++n) C[off + n * 16] = f2bf(acc[m][n][j]);
    }
}

// ---------------------------------------------------------------------------
// Final GEMM (ctx @ Wo^T), m97 structure, fp32 out.
// ---------------------------------------------------------------------------
__global__ __launch_bounds__(256, 2)
void gemm_out(const short* __restrict__ A, const short* __restrict__ B,
              float* __restrict__ C) {
  __shared__ __align__(16) short As[128 * 64];
  __shared__ __align__(16) short Bs[128 * 64];
  const int tid = threadIdx.x;
  const int lane = tid & 63;
  const int wid = tid >> 6;
  const int wr = wid >> 1, wc = wid & 1;
  const int g = lane >> 4, r = lane & 15;
  const int bm = blockIdx.y, bn = blockIdx.x;

  const f32x4 fz = {0.f, 0.f, 0.f, 0.f};
  f32x4 acc[4][4];
#pragma unroll
  for (int m = 0; m < 4; ++m)
#pragma unroll
    for (int n = 0; n < 4; ++n) acc[m][n] = fz;

  const short* Ab = A + (size_t)bm * 128 * GK;
  const short* Bb = B + (size_t)bn * 128 * GK;

  for (int kt = 0; kt < GK; kt += 64) {
#pragma unroll
    for (int i = 0; i < 4; ++i) {
      int c = i * 256 + tid;
      int row = c >> 3, c8 = c & 7;
      gload16(Ab + (size_t)row * GK + kt + c8 * 8, As + c * 8);
      gload16(Bb + (size_t)row * GK + kt + c8 * 8, Bs + c * 8);
    }
    __syncthreads();
#pragma unroll
    for (int kk = 0; kk < 2; ++kk) {
      s16x8 af[4], bf[4];
#pragma unroll
      for (int m = 0; m < 4; ++m)
        af[m] = *reinterpret_cast<const s16x8*>(As + (wr * 64 + m * 16 + r) * 64 + kk * 32 + g * 8);
#pragma unroll
      for (int n = 0; n < 4; ++n)
        bf[n] = *reinterpret_cast<const s16x8*>(Bs + (wc * 64 + n * 16 + r) * 64 + kk * 32 + g * 8);
#pragma unroll
      for (int m = 0; m < 4; ++m)
#pragma unroll
        for (int n = 0; n < 4; ++n) acc[m][n] = MFMA_BF16(af[m], bf[n], acc[m][n]);
    }
    __syncthreads();
  }

#pragma unroll
  for (int m = 0; m < 4; ++m)
#pragma unroll
    for (int j = 0; j < 4; ++j) {
      int crow = bm * 128 + wr * 64 + m * 16 + g * 4 + j;
      size_t off = (size_t)crow * 2048 + bn * 128 + wc * 64 + r;
#pragma unroll
      for (int n = 0; n < 4; ++n) C[off + n * 16] = acc[m][n][j];
    }
}

// ---------------------------------------------------------------------------
// MFMA flash attention — r15 structure (4 waves, 32 q-rows/wave, KVBLK=64,
// T14 prefetch, pre-transposed V with b128 staging + chunk-XOR swizzle)
// + r16-proven XCD-chunked block swizzle (K/V L2-resident).
// ---------------------------------------------------------------------------
__global__ __launch_bounds__(256, 2)
void attn(const short* __restrict__ Q, const short* __restrict__ K,
          const short* __restrict__ VT, short* __restrict__ O) {
  __shared__ __align__(16) short Ks[64 * 136];
  __shared__ __align__(16) short Vt[128 * 72];
  __shared__ __align__(16) short Ps[4][2][16 * 72];

  const int tid = threadIdx.x;
  const int lane = tid & 63;
  const int wid = tid >> 6;                  // 0..3
  const int g = lane >> 4, r = lane & 15;

  // XCD-chunked bijective swizzle (512 blocks, 512%8==0): XCD n hosts 4
  // consecutive bh -> K/V working set 4MB/XCD (L2-fit). [r16-proven]
  const int dflat = blockIdx.x + (blockIdx.y << 4);
  const int cflat = ((dflat & 7) << 6) + (dflat >> 3);
  const int qb = cflat & 15;
  const int bh = cflat >> 4;
  const int b = bh >> 4, h = bh & 15;
  const size_t base = (size_t)b * SL * EMB + (size_t)h * HD;
  const size_t vbase = (size_t)h * HD * 4096 + (size_t)b * SL;  // VpT origin

  const int q0 = qb * 128 + wid * 32;        // wave's first q-row (32 rows)
  s16x8 qf[2][4];
#pragma unroll
  for (int s = 0; s < 2; ++s)
#pragma unroll
    for (int kk = 0; kk < 4; ++kk)
      qf[s][kk] = *reinterpret_cast<const s16x8*>(
          Q + base + (size_t)(q0 + s * 16 + r) * EMB + kk * 32 + g * 8);

  const f32x4 fz = {0.f, 0.f, 0.f, 0.f};
  float l_run[2][4];
  f32x4 acc_o[2][8];
#pragma unroll
  for (int s = 0; s < 2; ++s) {
#pragma unroll
    for (int i = 0; i < 4; ++i) l_run[s][i] = 0.f;
#pragma unroll
    for (int i = 0; i < 8; ++i) acc_o[s][i] = fz;
  }

  const float SCALE = 0.08838834764831845f;  // 1/sqrt(128)
  const float C50I = 0.02f;                  // 1/50
  const float CA = -1.f / 3.f, CB = 2.f / 15.f;

  // ---- T14 prologue: tile 0 -> registers ----
  const int rk = tid >> 4, ck = tid & 15;    // K: [64 rows][16 chunks], 4 iters
  const int rv = tid >> 3, cv = tid & 7;     // V: [128 rows][8 chunks], 4 iters
  const int cvx = cv ^ (rv & 7);             // phys chunk for LDS write
  s16x8 kreg[4], vreg[4];
#pragma unroll
  for (int i = 0; i < 4; ++i) {
    kreg[i] = *reinterpret_cast<const s16x8*>(K + base + (size_t)(rk + i * 16) * EMB + ck * 8);
    vreg[i] = *reinterpret_cast<const s16x8*>(VT + vbase + (size_t)(rv + i * 32) * 4096 + cv * 8);
  }

  for (int t = 0; t < SL / 64; ++t) {
    __syncthreads();                         // prev tile's readers done
    // ---- write-late: regs -> LDS (all b128) ----
#pragma unroll
    for (int i = 0; i < 4; ++i) {
      *reinterpret_cast<s16x8*>(&Ks[(rk + i * 16) * 136 + ck * 8]) = kreg[i];
      *reinterpret_cast<s16x8*>(&Vt[(rv + i * 32) * 72 + (cvx << 3)]) = vreg[i];
    }
    __syncthreads();                         // staging visible

    // ---- issue-early: next tile's loads ----
    if (t + 1 < SL / 64) {
      const int kv1 = (t + 1) * 64;
#pragma unroll
      for (int i = 0; i < 4; ++i) {
        kreg[i] = *reinterpret_cast<const s16x8*>(K + base + (size_t)(kv1 + rk + i * 16) * EMB + ck * 8);
        vreg[i] = *reinterpret_cast<const s16x8*>(VT + vbase + (size_t)(rv + i * 32) * 4096 + kv1 + cv * 8);
      }
    }

    // ---- S = Q K^T : each kf read feeds both q-sets ----
    f32x4 sv[2][4];
#pragma unroll
    for (int kn = 0; kn < 4; ++kn) {
      sv[0][kn] = fz; sv[1][kn] = fz;
#pragma unroll
      for (int kk = 0; kk < 4; ++kk) {
        s16x8 kf = *reinterpret_cast<const s16x8*>(&Ks[(kn * 16 + r) * 136 + kk * 32 + g * 8]);
        sv[0][kn] = MFMA_BF16(qf[0][kk], kf, sv[0][kn]);
        sv[1][kn] = MFMA_BF16(qf[1][kk], kf, sv[1][kn]);
      }
    }

    // ---- poly softcap + fixed-max-50 softmax (lane-local) ----
#pragma unroll
    for (int s = 0; s < 2; ++s)
#pragma unroll
      for (int kn = 0; kn < 4; ++kn)
#pragma unroll
        for (int reg = 0; reg < 4; ++reg) {
          float z = sv[s][kn][reg] * SCALE;
          float x = z * C50I;
          float x2 = x * x;
          float poly = __builtin_fmaf(x2, __builtin_fmaf(x2, CB, CA), 1.f);
          float cap = fminf(z * poly, 50.f);
          float pe = __expf(cap - 50.f);
          l_run[s][reg] += pe;
          sv[s][kn][reg] = pe;
        }

    // ---- P -> LDS (bf16), wave-private, A-operand layout ----
#pragma unroll
    for (int s = 0; s < 2; ++s)
#pragma unroll
      for (int kn = 0; kn < 4; ++kn)
#pragma unroll
        for (int reg = 0; reg < 4; ++reg)
          Ps[wid][s][(g * 4 + reg) * 72 + kn * 16 + r] = f2bf(sv[s][kn][reg]);

    // ---- O += P V : each vf read feeds both q-sets ----
#pragma unroll
    for (int c = 0; c < 2; ++c) {
      s16x8 pa0 = *reinterpret_cast<const s16x8*>(&Ps[wid][0][r * 72 + c * 32 + g * 8]);
      s16x8 pa1 = *reinterpret_cast<const s16x8*>(&Ps[wid][1][r * 72 + c * 32 + g * 8]);
#pragma unroll
      for (int dn = 0; dn < 8; ++dn) {
        int d = dn * 16 + r;
        int pc = ((c * 4 + g) ^ (r & 7));               // phys chunk on read
        s16x8 vf = *reinterpret_cast<const s16x8*>(&Vt[d * 72 + (pc << 3)]);
        acc_o[0][dn] = MFMA_BF16(pa0, vf, acc_o[0][dn]);
        acc_o[1][dn] = MFMA_BF16(pa1, vf, acc_o[1][dn]);
      }
    }
  }

  // ---- deferred l reduction + epilogue (both sets) ----
#pragma unroll
  for (int s = 0; s < 2; ++s) {
#pragma unroll
    for (int reg = 0; reg < 4; ++reg) {
#pragma unroll
      for (int off = 1; off < 16; off <<= 1)
        l_run[s][reg] += __shfl_xor(l_run[s][reg], off);
      l_run[s][reg] = 1.f / l_run[s][reg];
    }
#pragma unroll
    for (int dn = 0; dn < 8; ++dn)
#pragma unroll
      for (int reg = 0; reg < 4; ++reg) {
        int row = q0 + s * 16 + g * 4 + reg;
        O[base + (size_t)row * EMB + dn * 16 + r] = f2bf(acc_o[s][dn][reg] * l_run[s][reg]);
      }
  }
}

__global__ void fill_f32(float* p, int n, float val) {
  int i = blockIdx.x * blockDim.x + threadIdx.x;
  if (i < n) p[i] = val;
}

// ---------------------------------------------------------------------------
extern "C" void kernel_launch(void* const* d_in, const int* in_sizes, int n_in,
                              void* d_out, int out_size, void* d_ws, size_t ws_size,
                              hipStream_t stream) {
  const float* q  = (const float*)d_in[0];
  const float* k  = (const float*)d_in[1];
  const float* v  = (const float*)d_in[2];
  const float* wq = (const float*)d_in[3];
  const float* wk = (const float*)d_in[4];
  const float* wv = (const float*)d_in[5];
  const float* wo = (const float*)d_in[6];
  float* out = (float*)d_out;

  bool ok = (n_in == 7) && out_size == 8388608;
  for (int i = 0; i < 3 && ok; ++i) ok = (in_sizes[i] == 8388608);
  for (int i = 3; i < 7 && ok; ++i) ok = (in_sizes[i] == 4194304);
  if (!ok) {
    fill_f32<<<(out_size + 255) / 256, 256, 0, stream>>>(out, out_size, 150.f);
    return;
  }

  const size_t NA = 8388608;
  const size_t NW = 4194304;
  const size_t need = (3 * NA + 4 * NW + 4 * NA) * sizeof(short); // 144 MiB
  if (ws_size < need) {
    fill_f32<<<(out_size + 255) / 256, 256, 0, stream>>>(out, out_size, 128.f);
    return;
  }

  short* bq  = (short*)d_ws;                 // cvt dst, contiguous
  short* bk  = bq + NA;
  short* bv  = bk + NA;
  short* bwq = bv + NA;
  short* bwk = bwq + NW;
  short* bwv = bwk + NW;
  short* bwo = bwv + NW;
  short* Qp  = bwo + NW;
  short* Kp  = Qp + NA;
  short* VpT = Kp + NA;                      // [2048 features][4096 tokens]
  short* Cx  = VpT + NA;

  dim3 blk(256);
  dim3 g3(16, 32, 3);                        // fused QKV
  dim3 gg(16, 32);                           // out GEMM
  dim3 ga(16, 32);                           // attn: 512 blocks

  cvt_all<<<2048, 256, 0, stream>>>(q, k, v, wq, wk, wv, wo, bq);
  gemm_qkv<<<g3, blk, 0, stream>>>(bq, bk, bwq, bwk, bwv, bv, Qp, Kp, VpT);
  attn<<<ga, blk, 0, stream>>>(Qp, Kp, VpT, Cx);
  gemm_out<<<gg, blk, 0, stream>>>(Cx, bwo, out);
}